// Round 7
// baseline (540.734 us; speedup 1.0000x reference)
//
#include <hip/hip_runtime.h>
#include <stdint.h>

// Problem dims (fixed)
constexpr int T_DIM   = 16384;
constexpr int IN_DIM  = 4096;
constexpr int OUT_DIM = 4096;

using int32x4 = __attribute__((ext_vector_type(4))) int;

#define GLOAD_LDS16(g, l)                                                     \
    __builtin_amdgcn_global_load_lds(                                         \
        (const __attribute__((address_space(1))) void*)(uintptr_t)(g),        \
        (__attribute__((address_space(3))) void*)(uintptr_t)(l), 16, 0, 0)

// ===========================================================================
// Pre-pass: int32 (int8-valued) -> packed int8, pre-swizzled: within each
// 64-B group of 4 chunks, stored = chunk ^ ((row>>1)&3).  (rule #21)
// ===========================================================================
__global__ void pack_swz(const int* __restrict__ src, int8_t* __restrict__ dst,
                         int rows, int cols) {
    int64_t tid = (int64_t)blockIdx.x * blockDim.x + threadIdx.x;
    int64_t nchunks = (int64_t)rows * (cols / 16);
    if (tid >= nchunks) return;
    int row  = (int)(tid / (cols / 16));
    int cidx = (int)(tid % (cols / 16));
    const int32x4* s4 =
        reinterpret_cast<const int32x4*>(src + (int64_t)row * cols + (cidx << 4));
    uint32_t p[4];
#pragma unroll
    for (int v = 0; v < 4; ++v) {
        int32x4 t = s4[v];
        p[v] = (uint32_t)(t[0] & 0xff) | ((uint32_t)(t[1] & 0xff) << 8) |
               ((uint32_t)(t[2] & 0xff) << 16) | ((uint32_t)(t[3] & 0xff) << 24);
    }
    int cs = (cidx & ~3) | ((cidx & 3) ^ ((row >> 1) & 3));
    *reinterpret_cast<int32x4*>(dst + (int64_t)row * cols + (cs << 4)) =
        *reinterpret_cast<int32x4*>(p);
}

// ===========================================================================
// Main GEMM: 256x256 tile, BK=64 int8, 8 waves (2Mx4N), per-wave 128x64.
// 4-buffer LDS pipeline (128 KiB), counted vmcnt(4).
// THIS ROUND: register double-buffered fragments — tile t's body issues the
// ds_reads for tile t+1 (into the OTHER frag set) and then runs tile t's 32
// MFMAs on fragments read LAST tile. The LDS pipe services t+1's reads while
// the matrix pipe chews t's MFMAs (they were serialized before: 1300cy+1500cy
// back-to-back = the 38% MfmaUtil wall). Compiler emits the counted lgkm wait
// (leaves the 12 new reads in flight) since all deps are register-visible.
// Boundary: vmcnt(4) ensures buf(t+2) complete before tile t+1 reads it.
// WAR safety: stage(t+3) -> buf(t-1)&3, whose readers (frag reads issued in
// tile t-2) completed before tile t-1's MFMAs, a full barrier earlier.
// ===========================================================================
constexpr int BM = 256, BN = 256, BK = 64;
constexpr int NT    = IN_DIM / BK;     // 64
constexpr int ATILE = BM * BK;         // 16 KiB
constexpr int BUFSZ = 2 * ATILE;       // 32 KiB (A + B)

__global__ __launch_bounds__(512, 2)
void gemm_i8_8p(const int8_t* __restrict__ x8, const int8_t* __restrict__ w8,
                const int* __restrict__ bias, const float* __restrict__ alphap,
                const float* __restrict__ betap, int* __restrict__ out) {
    __shared__ __align__(16) int8_t lds[4 * BUFSZ];   // 128 KiB

    const int tid  = threadIdx.x;
    const int lane = tid & 63;
    const int wid  = tid >> 6;
    const int wr   = wid >> 2;   // 0..1
    const int wc   = wid & 3;    // 0..3

    // XCD-chunked bijective swizzle (nwg = 1024, %8==0)
    const int nwg = gridDim.x;
    const int cpx = nwg >> 3;
    const int bid = blockIdx.x;
    const int swz = (bid & 7) * cpx + (bid >> 3);
    const int bm  = swz >> 4;    // 64 M-blocks
    const int bn  = swz & 15;    // 16 N-blocks
    const int brow = bm * BM;
    const int bcol = bn * BN;

    const float alpha = *alphap;
    const float beta  = *betap;

    const int g = lane >> 4;     // K-chunk 0..3 (16 int8 each)
    const int r = lane & 15;

    // ---- hoisted staging addresses: 4 moving global pointers (+BK/tile)
    const int offL0 = tid * 16;            // half 0: rows 0..127
    const int offL1 = 8192 + tid * 16;     // half 1: rows 128..255
    const int rowL0 = offL0 >> 6, inL0 = offL0 & 63;
    const int rowL1 = offL1 >> 6, inL1 = offL1 & 63;
    const int8_t* pA0 = x8 + (int64_t)(brow + rowL0) * IN_DIM + inL0;
    const int8_t* pA1 = x8 + (int64_t)(brow + rowL1) * IN_DIM + inL1;
    const int8_t* pB0 = w8 + (int64_t)(bcol + rowL0) * IN_DIM + inL0;
    const int8_t* pB1 = w8 + (int64_t)(bcol + rowL1) * IN_DIM + inL1;
    const int dA0 = offL0, dA1 = offL1;
    const int dB0 = ATILE + offL0, dB1 = ATILE + offL1;

    // ---- hoisted fragment byte-offsets (buffer-invariant; swizzle baked in)
    int aoff[8], boff[4];
#pragma unroll
    for (int m = 0; m < 8; ++m) {
        const int row = wr * 128 + m * 16 + r;
        aoff[m] = row * BK + ((g ^ ((row >> 1) & 3)) << 4);
    }
#pragma unroll
    for (int n = 0; n < 4; ++n) {
        const int row = wc * 64 + n * 16 + r;
        boff[n] = ATILE + row * BK + ((g ^ ((row >> 1) & 3)) << 4);
    }

    int32x4 acc[8][4] = {};
    int32x4 fA0[8], fB0[4], fA1[8], fB1[4];   // ping-pong fragment sets

#define STAGE4(BIDX)                                                           \
    do {                                                                       \
        int8_t* nb = lds + (BIDX) * BUFSZ;                                     \
        GLOAD_LDS16(pA0, nb + dA0);  GLOAD_LDS16(pA1, nb + dA1);               \
        GLOAD_LDS16(pB0, nb + dB0);  GLOAD_LDS16(pB1, nb + dB1);               \
        pA0 += BK; pA1 += BK; pB0 += BK; pB1 += BK;                            \
    } while (0)

    // Tile body: stage(t+3), read frags(t+1)->Fn, MFMA on Fc, boundary.
    // VM: 4 = steady, 0 = drain, -1 = none.
#define TILE(READB, STAGEB, FAC, FBC, FAN, FBN, PF, VM)                        \
    do {                                                                       \
        if (PF) STAGE4(STAGEB);                                                \
        const int8_t* rb = lds + (READB) * BUFSZ;                              \
        _Pragma("unroll") for (int n = 0; n < 4; ++n)                          \
            FBN[n] = *reinterpret_cast<const int32x4*>(rb + boff[n]);          \
        _Pragma("unroll") for (int m = 0; m < 8; ++m)                          \
            FAN[m] = *reinterpret_cast<const int32x4*>(rb + aoff[m]);          \
        __builtin_amdgcn_s_setprio(1);                                         \
        _Pragma("unroll") for (int m = 0; m < 8; ++m)                          \
            _Pragma("unroll") for (int n = 0; n < 4; ++n)                      \
                acc[m][n] = __builtin_amdgcn_mfma_i32_16x16x64_i8(             \
                    FAC[m], FBC[n], acc[m][n], 0, 0, 0);                       \
        __builtin_amdgcn_s_setprio(0);                                         \
        if ((VM) == 4)      asm volatile("s_waitcnt vmcnt(4)" ::: "memory");   \
        else if ((VM) == 0) asm volatile("s_waitcnt vmcnt(0)" ::: "memory");   \
        __builtin_amdgcn_s_barrier();                                          \
        asm volatile("" ::: "memory");                                         \
    } while (0)

    // Prologue: stage tiles 0,1,2; wait buf0 AND buf1 (tile 0 body reads
    // buf1); read tile-0 fragments into F0.
    STAGE4(0); STAGE4(1); STAGE4(2);
    asm volatile("s_waitcnt vmcnt(4)" ::: "memory");
    __builtin_amdgcn_s_barrier();
    asm volatile("" ::: "memory");
#pragma unroll
    for (int n = 0; n < 4; ++n)
        fB0[n] = *reinterpret_cast<const int32x4*>(lds + boff[n]);
#pragma unroll
    for (int m = 0; m < 8; ++m)
        fA0[m] = *reinterpret_cast<const int32x4*>(lds + aoff[m]);

    // Main loop: tiles 0..59, 4-tile unroll, all indices literal.
    // parity: t%4=0: cur F0, read buf1 -> F1, stage buf3
    //         t%4=1: cur F1, read buf2 -> F0, stage buf0
    //         t%4=2: cur F0, read buf3 -> F1, stage buf1
    //         t%4=3: cur F1, read buf0 -> F0, stage buf2
#pragma unroll 1
    for (int tt = 0; tt < NT - 4; tt += 4) {
        TILE(1, 3, fA0, fB0, fA1, fB1, true, 4);
        TILE(2, 0, fA1, fB1, fA0, fB0, true, 4);
        TILE(3, 1, fA0, fB0, fA1, fB1, true, 4);
        TILE(0, 2, fA1, fB1, fA0, fB0, true, 4);
    }
    // Tail: tiles 60..63. t=60 stages 63 (last); drain vmcnt 4->0.
    TILE(1, 3, fA0, fB0, fA1, fB1, true,  4);   // t=60
    TILE(2, 0, fA1, fB1, fA0, fB0, false, 0);   // t=61
    TILE(3, 0, fA0, fB0, fA1, fB1, false, -1);  // t=62
    // t=63: MFMA only on F1 (compiler waits lgkm for its reads).
    __builtin_amdgcn_s_setprio(1);
#pragma unroll
    for (int m = 0; m < 8; ++m)
#pragma unroll
        for (int n = 0; n < 4; ++n)
            acc[m][n] = __builtin_amdgcn_mfma_i32_16x16x64_i8(
                fA1[m], fB1[n], acc[m][n], 0, 0, 0);
    __builtin_amdgcn_s_setprio(0);
#undef TILE
#undef STAGE4

    // Epilogue: y = acc*alpha + bias*beta, round, clip, store int32.
    // C/D: col = lane&15, row = (lane>>4)*4 + j.
    const int r4 = (lane >> 4) * 4;
    const int cl = lane & 15;
#pragma unroll
    for (int n = 0; n < 4; ++n) {
        const int col = bcol + wc * 64 + n * 16 + cl;
        const float bterm = (float)bias[col] * beta;
#pragma unroll
        for (int m = 0; m < 8; ++m) {
            const int row0 = brow + wr * 128 + m * 16 + r4;
#pragma unroll
            for (int j = 0; j < 4; ++j) {
                float y = (float)acc[m][n][j] * alpha + bterm;
                y = rintf(y);
                y = fminf(fmaxf(y, -128.0f), 127.0f);
                out[(int64_t)(row0 + j) * OUT_DIM + col] = (int)y;
            }
        }
    }
}

// ===========================================================================
// Fallback (ws too small): reads int32 inputs directly, packs in regs,
// swizzled ds_write. 128x128 tile. Known-correct (round 2).
// ===========================================================================
__global__ __launch_bounds__(256)
void gemm_i8_fb(const int* __restrict__ x32, const int* __restrict__ w32,
                const int* __restrict__ bias, const float* __restrict__ alphap,
                const float* __restrict__ betap, int* __restrict__ out) {
    constexpr int FBM = 128, FBK = 128;
    __shared__ int8_t lA[FBM * FBK];
    __shared__ int8_t lB[FBM * FBK];

    const int tid  = threadIdx.x;
    const int wid  = tid >> 6;
    const int lane = tid & 63;
    const int nwg = gridDim.x;
    const int cpx = nwg >> 3;
    const int bid = blockIdx.x;
    const int swz = (bid & 7) * cpx + (bid >> 3);
    const int brow = (swz >> 5) * FBM;
    const int bcol = (swz & 31) * FBM;
    const int wr = wid >> 1, wc = wid & 1;
    const float alpha = *alphap;
    const float beta  = *betap;

    int32x4 acc[4][4] = {};
    for (int kt = 0; kt < IN_DIM / FBK; ++kt) {
        const int64_t kbase = (int64_t)kt * FBK;
#pragma unroll
        for (int q = 0; q < 4; ++q) {
            const int off = wid * 4096 + q * 1024 + lane * 16;
            const int row = off >> 7;
            const int k   = off & 127;
            const int* ga = x32 + (int64_t)(brow + row) * IN_DIM + kbase + k;
            const int* gb = w32 + (int64_t)(bcol + row) * IN_DIM + kbase + k;
            uint32_t pa[4], pb[4];
#pragma unroll
            for (int v = 0; v < 4; ++v) {
                int32x4 ta = reinterpret_cast<const int32x4*>(ga)[v];
                int32x4 tb = reinterpret_cast<const int32x4*>(gb)[v];
                pa[v] = (uint32_t)(ta[0] & 0xff) | ((uint32_t)(ta[1] & 0xff) << 8) |
                        ((uint32_t)(ta[2] & 0xff) << 16) | ((uint32_t)(ta[3] & 0xff) << 24);
                pb[v] = (uint32_t)(tb[0] & 0xff) | ((uint32_t)(tb[1] & 0xff) << 8) |
                        ((uint32_t)(tb[2] & 0xff) << 16) | ((uint32_t)(tb[3] & 0xff) << 24);
            }
            const int sc = ((k >> 4) ^ (row & 7)) << 4;
            *reinterpret_cast<int32x4*>(lA + row * FBK + sc) = *reinterpret_cast<int32x4*>(pa);
            *reinterpret_cast<int32x4*>(lB + row * FBK + sc) = *reinterpret_cast<int32x4*>(pb);
        }
        __syncthreads();
#pragma unroll
        for (int ks = 0; ks < 2; ++ks) {
            const int gg = lane >> 4, rr = lane & 15;
            const int lc = ks * 4 + gg;
            int32x4 af[4], bf[4];
#pragma unroll
            for (int m = 0; m < 4; ++m) {
                const int row = wr * 64 + m * 16 + rr;
                af[m] = *reinterpret_cast<const int32x4*>(lA + row * FBK + ((lc ^ (row & 7)) << 4));
            }
#pragma unroll
            for (int n = 0; n < 4; ++n) {
                const int row = wc * 64 + n * 16 + rr;
                bf[n] = *reinterpret_cast<const int32x4*>(lB + row * FBK + ((lc ^ (row & 7)) << 4));
            }
#pragma unroll
            for (int m = 0; m < 4; ++m)
#pragma unroll
                for (int n = 0; n < 4; ++n)
                    acc[m][n] = __builtin_amdgcn_mfma_i32_16x16x64_i8(af[m], bf[n], acc[m][n], 0, 0, 0);
        }
        __syncthreads();
    }
    const int r4 = (lane >> 4) * 4;
    const int cl = lane & 15;
#pragma unroll
    for (int n = 0; n < 4; ++n) {
        const int col = bcol + wc * 64 + n * 16 + cl;
        const float bterm = (float)bias[col] * beta;
#pragma unroll
        for (int m = 0; m < 4; ++m) {
            const int row0 = brow + wr * 64 + m * 16 + r4;
#pragma unroll
            for (int j = 0; j < 4; ++j) {
                float y = (float)acc[m][n][j] * alpha + bterm;
                y = rintf(y);
                y = fminf(fmaxf(y, -128.0f), 127.0f);
                out[(int64_t)(row0 + j) * OUT_DIM + col] = (int)y;
            }
        }
    }
}

// ===========================================================================
extern "C" void kernel_launch(void* const* d_in, const int* in_sizes, int n_in,
                              void* d_out, int out_size, void* d_ws, size_t ws_size,
                              hipStream_t stream) {
    const int*   x     = (const int*)d_in[0];
    const int*   w     = (const int*)d_in[1];
    const int*   bias  = (const int*)d_in[2];
    const float* alpha = (const float*)d_in[3];
    const float* beta  = (const float*)d_in[4];
    int*         out   = (int*)d_out;

    const size_t need = (size_t)T_DIM * IN_DIM + (size_t)OUT_DIM * IN_DIM;

    if (ws_size >= need) {
        int8_t* x8 = (int8_t*)d_ws;
        int8_t* w8 = x8 + (size_t)T_DIM * IN_DIM;
        {
            int64_t nch = (int64_t)T_DIM * (IN_DIM / 16);
            pack_swz<<<(int)((nch + 255) / 256), 256, 0, stream>>>(x, x8, T_DIM, IN_DIM);
        }
        {
            int64_t nch = (int64_t)OUT_DIM * (IN_DIM / 16);
            pack_swz<<<(int)((nch + 255) / 256), 256, 0, stream>>>(w, w8, OUT_DIM, IN_DIM);
        }
        const int grid = (T_DIM / BM) * (OUT_DIM / BN);  // 1024
        gemm_i8_8p<<<grid, 512, 0, stream>>>(x8, w8, bias, alpha, beta, out);
    } else {
        const int grid = (T_DIM / 128) * (OUT_DIM / 128);  // 4096
        gemm_i8_fb<<<grid, 256, 0, stream>>>(x, w, bias, alpha, beta, out);
    }
}